// Round 1
// baseline (471.321 us; speedup 1.0000x reference)
//
#include <hip/hip_runtime.h>
#include <cstdint>

typedef __bf16 bf16;
typedef __attribute__((ext_vector_type(8))) __bf16 bf16x8;
typedef __attribute__((ext_vector_type(4))) __bf16 bf16x4;
typedef __attribute__((ext_vector_type(4))) float f32x4;

#define NROWS 100000
#define DIM   512
#define NC    400
#define NCP   416

// ---- workspace layout (bytes) ----
#define WS_WP    0u          // packed W bf16: 16*4*416*8 = 212992 elems = 425984 B
#define WS_SUMU  430080u     // 100 f32
#define WS_SUMV  430480u     // 100 f32
#define WS_DSC   430880u     // 1 f32
#define WS_VTZT  431104u     // VtZ*Dscale, transposed [112][128] bf16 = 28672 B
#define WS_U     524288u     // [100000][128] bf16 = 25600000 B
#define WS_V     26124288u   // [100000][100] bf16 = 20000000 B
#define WS_Z     46124288u   // [100000][100] bf16 = 20000000 B
#define WS_PART  66124288u   // 98 * 112*112 f32 = 4917248 B
#define WS_NEED  71041536u

__device__ __forceinline__ void gload_lds16(const void* g, void* l) {
  __builtin_amdgcn_global_load_lds(
      (const __attribute__((address_space(1))) uint32_t*)g,
      (__attribute__((address_space(3))) uint32_t*)l,
      16, 0, 0);
}

// ---- k1: pack W -> bf16 staging layout, zero sums ----
// wp index = ((t*4+g)*416 + n)*8 + e ; k = t*32 + 4g + (e<4 ? e : 12+e)
__global__ void k1_prep(const float* __restrict__ W, bf16* __restrict__ wp,
                        float* __restrict__ sums) {
  const int idx = blockIdx.x * 256 + threadIdx.x;
  if (idx < 200) sums[idx] = 0.f;
  if (idx >= 16 * 4 * 416 * 8) return;
  const int e = idx & 7;
  int rest = idx >> 3;
  const int n = rest % 416;
  rest /= 416;
  const int g = rest & 3;
  const int t = rest >> 2;
  const int k = t * 32 + 4 * g + ((e < 4) ? e : (12 + e));
  float v = 0.f;
  if (n < NC) v = W[n * DIM + k];
  wp[idx] = (bf16)v;
}

// ---- k2: tmp = relu(X@Wt+b); write U/V/Z (bf16), T (f32->out), col sums ----
__global__ __launch_bounds__(512, 2) void k2_main(
    const float* __restrict__ X, const bf16* __restrict__ Wp,
    const float* __restrict__ bias, float* __restrict__ out,
    bf16* __restrict__ U, bf16* __restrict__ V, bf16* __restrict__ Z,
    float* __restrict__ sumU, float* __restrict__ sumV) {
  __shared__ __align__(16) bf16 lds[2][13312];   // 2 x 26624 B
  const int tid  = threadIdx.x;
  const int lane = tid & 63;
  const int wave = tid >> 6;
  const int wm = wave >> 1;   // 0..3  (row group)
  const int wn = wave & 1;    // 0..1  (col half)
  const int m  = lane & 15;
  const int g  = lane >> 4;
  const int rb = blockIdx.x * 128 + wm * 32;

  f32x4 acc[2][13];
#pragma unroll
  for (int i = 0; i < 2; ++i)
#pragma unroll
    for (int j = 0; j < 13; ++j) acc[i][j] = (f32x4){0.f, 0.f, 0.f, 0.f};

  int r0 = rb + m;      if (r0 > NROWS - 1) r0 = NROWS - 1;
  int r1 = rb + 16 + m; if (r1 > NROWS - 1) r1 = NROWS - 1;
  const float* xp0 = X + (size_t)r0 * DIM + 4 * g;
  const float* xp1 = X + (size_t)r1 * DIM + 4 * g;

  // prefetch A for t=0
  f32x4 a00 = *(const f32x4*)(xp0);
  f32x4 a01 = *(const f32x4*)(xp0 + 16);
  f32x4 a10 = *(const f32x4*)(xp1);
  f32x4 a11 = *(const f32x4*)(xp1 + 16);

  // stage t=0
  for (int c = wave; c < 26; c += 8)
    gload_lds16((const char*)Wp + c * 1024 + lane * 16, (char*)&lds[0][0] + c * 1024);
  __syncthreads();

  for (int t = 0; t < 16; ++t) {
    const int buf = t & 1;
    if (t < 15) {
      const char* gsrc = (const char*)Wp + (size_t)(t + 1) * 26624;
      for (int c = wave; c < 26; c += 8)
        gload_lds16(gsrc + c * 1024 + lane * 16, (char*)&lds[buf ^ 1][0] + c * 1024);
    }
    f32x4 n00, n01, n10, n11;
    if (t < 15) {
      const float* q0 = xp0 + (t + 1) * 32;
      const float* q1 = xp1 + (t + 1) * 32;
      n00 = *(const f32x4*)(q0); n01 = *(const f32x4*)(q0 + 16);
      n10 = *(const f32x4*)(q1); n11 = *(const f32x4*)(q1 + 16);
    }
    bf16x8 af0 = {(bf16)a00.x, (bf16)a00.y, (bf16)a00.z, (bf16)a00.w,
                  (bf16)a01.x, (bf16)a01.y, (bf16)a01.z, (bf16)a01.w};
    bf16x8 af1 = {(bf16)a10.x, (bf16)a10.y, (bf16)a10.z, (bf16)a10.w,
                  (bf16)a11.x, (bf16)a11.y, (bf16)a11.z, (bf16)a11.w};
    const bf16* lb = &lds[buf][0];
#pragma unroll
    for (int nf = 0; nf < 13; ++nf) {
      const int n = (wn * 13 + nf) * 16 + m;
      bf16x8 bfr = *(const bf16x8*)(lb + (g * 416 + n) * 8);
      acc[0][nf] = __builtin_amdgcn_mfma_f32_16x16x32_bf16(af0, bfr, acc[0][nf], 0, 0, 0);
      acc[1][nf] = __builtin_amdgcn_mfma_f32_16x16x32_bf16(af1, bfr, acc[1][nf], 0, 0, 0);
    }
    __syncthreads();
    a00 = n00; a01 = n01; a10 = n10; a11 = n11;
  }

  // epilogue: bias+relu, scatter U/V/Z/T, column sums
  float csum[13];
#pragma unroll
  for (int nf = 0; nf < 13; ++nf) csum[nf] = 0.f;

#pragma unroll
  for (int mf = 0; mf < 2; ++mf) {
#pragma unroll
    for (int nf = 0; nf < 13; ++nf) {
      const int c = (wn * 13 + nf) * 16 + m;
      const float bv = (c < NC) ? bias[c] : 0.f;
#pragma unroll
      for (int r = 0; r < 4; ++r) {
        const int row = rb + mf * 16 + 4 * g + r;
        float v = acc[mf][nf][r] + bv;
        v = fmaxf(v, 0.f);
        if (row < NROWS) {
          if (c < 128) U[(size_t)row * 128 + c] = (c < 100) ? (bf16)v : (bf16)0.f;
          if (c >= 100 && c < 200) V[(size_t)row * 100 + (c - 100)] = (bf16)v;
          if (c >= 200 && c < 300) Z[(size_t)row * 100 + (c - 200)] = (bf16)v;
          if (c >= 300 && c < 400) out[(size_t)row * 200 + 100 + (c - 300)] = v;
          if (c < 200) csum[nf] += v;
        }
      }
    }
  }
  if (wn == 0) {
#pragma unroll
    for (int nf = 0; nf < 13; ++nf) {
      float s = csum[nf];
      s += __shfl_xor(s, 16, 64);
      s += __shfl_xor(s, 32, 64);
      if (lane < 16) {
        const int c = nf * 16 + lane;
        if (c < 100) atomicAdd(&sumU[c], s);
        else if (c < 200) atomicAdd(&sumV[c - 100], s);
      }
    }
  }
}

// ---- k3: per-1024-row partial VtZ (112x112 padded) via MFMA ----
__global__ __launch_bounds__(256) void k3_vtz(
    const bf16* __restrict__ V, const bf16* __restrict__ Z,
    float* __restrict__ part) {
  __shared__ __align__(16) bf16 vt[112][132];
  __shared__ __align__(16) bf16 zt[112][132];
  const int tid = threadIdx.x;
  const int lane = tid & 63;
  const int wave = tid >> 6;
  const int m = lane & 15, g = lane >> 4;

  f32x4 acc[2][7];
#pragma unroll
  for (int i = 0; i < 2; ++i)
#pragma unroll
    for (int j = 0; j < 7; ++j) acc[i][j] = (f32x4){0.f, 0.f, 0.f, 0.f};

  const int rowbase = blockIdx.x * 1024;
  for (int ch = 0; ch < 8; ++ch) {
    const int r0 = rowbase + ch * 128;
    __syncthreads();
    for (int i = tid; i < 112 * 128; i += 256) {
      const int r = i / 112, c = i % 112;
      const int gr = r0 + r;
      bf16 vv = (bf16)0.f, zz = (bf16)0.f;
      if (c < 100 && gr < NROWS) {
        vv = V[(size_t)gr * 100 + c];
        zz = Z[(size_t)gr * 100 + c];
      }
      vt[c][r] = vv;
      zt[c][r] = zz;
    }
    __syncthreads();
#pragma unroll
    for (int ks = 0; ks < 4; ++ks) {
#pragma unroll
      for (int mi = 0; mi < 2; ++mi) {
        const int mf = wave + mi * 4;
        if (mf < 7) {
          const int i2 = mf * 16 + m;
          bf16x4 A0 = *(const bf16x4*)&vt[i2][ks * 32 + 4 * g];
          bf16x4 A1 = *(const bf16x4*)&vt[i2][ks * 32 + 16 + 4 * g];
          bf16x8 afr = {A0[0], A0[1], A0[2], A0[3], A1[0], A1[1], A1[2], A1[3]};
#pragma unroll
          for (int nf = 0; nf < 7; ++nf) {
            const int j2 = nf * 16 + m;
            bf16x4 B0 = *(const bf16x4*)&zt[j2][ks * 32 + 4 * g];
            bf16x4 B1 = *(const bf16x4*)&zt[j2][ks * 32 + 16 + 4 * g];
            bf16x8 bfr = {B0[0], B0[1], B0[2], B0[3], B1[0], B1[1], B1[2], B1[3]};
            acc[mi][nf] = __builtin_amdgcn_mfma_f32_16x16x32_bf16(afr, bfr, acc[mi][nf], 0, 0, 0);
          }
        }
      }
    }
  }
  float* pb = part + (size_t)blockIdx.x * 12544;
#pragma unroll
  for (int mi = 0; mi < 2; ++mi) {
    const int mf = wave + mi * 4;
    if (mf < 7) {
#pragma unroll
      for (int nf = 0; nf < 7; ++nf)
#pragma unroll
        for (int r = 0; r < 4; ++r) {
          const int ii = mf * 16 + 4 * g + r;
          const int jj = nf * 16 + m;
          pb[ii * 112 + jj] = acc[mi][nf][r];
        }
    }
  }
}

// ---- k4a: Dscale ----
__global__ void k4a_norm(const float* __restrict__ sumU, const float* __restrict__ sumV,
                         float* __restrict__ dsc) {
  const int l = threadIdx.x;  // 64
  float v = 0.f;
  if (l < 50) v = sumU[l] * sumV[l] + sumU[l + 50] * sumV[l + 50];
#pragma unroll
  for (int off = 32; off > 0; off >>= 1) v += __shfl_down(v, off, 64);
  if (l == 0) dsc[0] = 1.f / (v * (1.f / (float)NROWS) + 1e-6f);
}

// ---- k4b: reduce partials, scale, store transposed bf16 [j][128] ----
__global__ void k4b_reduce(const float* __restrict__ part, const float* __restrict__ dsc,
                           bf16* __restrict__ vtzt) {
  const int idx = blockIdx.x * 256 + threadIdx.x;
  if (idx >= 128 * 112) return;
  const int i = idx / 112;   // k index 0..127
  const int j = idx % 112;
  float s = 0.f;
  if (i < 112) {
    for (int bb = 0; bb < 98; ++bb) s += part[(size_t)bb * 12544 + idx];
    s *= dsc[0];
  }
  vtzt[j * 128 + i] = (bf16)s;
}

// ---- k5: res = U @ VtZS -> out[:, 0:100] ----
__global__ __launch_bounds__(256) void k5_res(
    const bf16* __restrict__ U, const bf16* __restrict__ vtzt,
    float* __restrict__ out) {
  const int tid = threadIdx.x;
  const int lane = tid & 63;
  const int wave = tid >> 6;
  const int m = lane & 15, g = lane >> 4;
  const int rb = blockIdx.x * 128 + wave * 32;

  f32x4 acc[2][7];
#pragma unroll
  for (int i = 0; i < 2; ++i)
#pragma unroll
    for (int j = 0; j < 7; ++j) acc[i][j] = (f32x4){0.f, 0.f, 0.f, 0.f};

  int r0 = rb + m;      if (r0 > NROWS - 1) r0 = NROWS - 1;
  int r1 = rb + 16 + m; if (r1 > NROWS - 1) r1 = NROWS - 1;
  const bf16* u0 = U + (size_t)r0 * 128 + 4 * g;
  const bf16* u1 = U + (size_t)r1 * 128 + 4 * g;
  const bf16* vb = vtzt + 4 * g;

#pragma unroll
  for (int ks = 0; ks < 4; ++ks) {
    bf16x4 A00 = *(const bf16x4*)(u0 + ks * 32);
    bf16x4 A01 = *(const bf16x4*)(u0 + ks * 32 + 16);
    bf16x4 A10 = *(const bf16x4*)(u1 + ks * 32);
    bf16x4 A11 = *(const bf16x4*)(u1 + ks * 32 + 16);
    bf16x8 af0 = {A00[0], A00[1], A00[2], A00[3], A01[0], A01[1], A01[2], A01[3]};
    bf16x8 af1 = {A10[0], A10[1], A10[2], A10[3], A11[0], A11[1], A11[2], A11[3]};
#pragma unroll
    for (int nf = 0; nf < 7; ++nf) {
      const int n = nf * 16 + m;
      bf16x4 B0 = *(const bf16x4*)(vb + n * 128 + ks * 32);
      bf16x4 B1 = *(const bf16x4*)(vb + n * 128 + ks * 32 + 16);
      bf16x8 bfr = {B0[0], B0[1], B0[2], B0[3], B1[0], B1[1], B1[2], B1[3]};
      acc[0][nf] = __builtin_amdgcn_mfma_f32_16x16x32_bf16(af0, bfr, acc[0][nf], 0, 0, 0);
      acc[1][nf] = __builtin_amdgcn_mfma_f32_16x16x32_bf16(af1, bfr, acc[1][nf], 0, 0, 0);
    }
  }
#pragma unroll
  for (int mf = 0; mf < 2; ++mf)
#pragma unroll
    for (int nf = 0; nf < 7; ++nf)
#pragma unroll
      for (int r = 0; r < 4; ++r) {
        const int row = rb + mf * 16 + 4 * g + r;
        const int c = nf * 16 + m;
        if (row < NROWS && c < 100)
          out[(size_t)row * 200 + c] = acc[mf][nf][r];
      }
}

extern "C" void kernel_launch(void* const* d_in, const int* in_sizes, int n_in,
                              void* d_out, int out_size, void* d_ws, size_t ws_size,
                              hipStream_t stream) {
  const float* X = (const float*)d_in[0];
  const float* W = (const float*)d_in[1];
  const float* b = (const float*)d_in[2];
  float* out = (float*)d_out;
  char* ws = (char*)d_ws;
  if (ws_size < WS_NEED) return;  // workspace too small: fail loudly via mismatch

  bf16* wp    = (bf16*)(ws + WS_WP);
  float* sumU = (float*)(ws + WS_SUMU);
  float* sumV = (float*)(ws + WS_SUMV);
  float* dsc  = (float*)(ws + WS_DSC);
  bf16* vtzt  = (bf16*)(ws + WS_VTZT);
  bf16* U     = (bf16*)(ws + WS_U);
  bf16* V     = (bf16*)(ws + WS_V);
  bf16* Z     = (bf16*)(ws + WS_Z);
  float* part = (float*)(ws + WS_PART);

  k1_prep<<<832, 256, 0, stream>>>(W, wp, sumU);
  k2_main<<<782, 512, 0, stream>>>(X, wp, b, out, U, V, Z, sumU, sumV);
  k3_vtz<<<98, 256, 0, stream>>>(V, Z, part);
  k4a_norm<<<1, 64, 0, stream>>>(sumU, sumV, dsc);
  k4b_reduce<<<56, 256, 0, stream>>>(part, dsc, vtzt);
  k5_res<<<782, 256, 0, stream>>>(U, vtzt, out);
}

// Round 2
// 372.889 us; speedup vs baseline: 1.2640x; 1.2640x over previous
//
#include <hip/hip_runtime.h>
#include <cstdint>

typedef __bf16 bf16;
typedef __attribute__((ext_vector_type(8))) __bf16 bf16x8;
typedef __attribute__((ext_vector_type(4))) __bf16 bf16x4;
typedef __attribute__((ext_vector_type(4))) float f32x4;

#define NROWS 100000
#define DIM   512
#define NC    400
#define NCP   448   // packed W columns (4 quarters of 112)

// ---- workspace layout (bytes) ---- (proven bound: ws >= 71041536 from round 1)
#define WS_WP    0u          // packed W bf16: 16*4*448*8 = 229376 elems = 458752 B (dead after k2 -> reused as PART2)
#define WS_SUMU  458752u     // 100 f32
#define WS_SUMV  459152u     // 100 f32
#define WS_DSC   459552u     // 1 f32
#define WS_VTZT  459776u     // VtZ*Dscale, transposed [112][128] bf16 = 28672 B
#define WS_U     524288u     // [100000][128] bf16 = 25600000 B
#define WS_VT    26124288u   // V^T [100][100000] bf16 = 20000000 B
#define WS_ZT    46124288u   // Z^T [100][100000] bf16 = 20000000 B
#define WS_PART  66124288u   // 196 x 12544 bf16 = 4917248 B -> ends exactly 71041536
#define WS_NEED  71041536u
#define WS_PART2 WS_WP       // 7 x 12544 f32 = 351232 B (fits in dead wp region)

// ---- k1: pack W -> bf16 staging layout (448 cols, zero-pad >=400), zero sums ----
// wp index = ((t*4+g)*448 + n)*8 + e ; k = t*32 + 4g + (e<4 ? e : 12+e)
__global__ void k1_prep(const float* __restrict__ W, bf16* __restrict__ wp,
                        float* __restrict__ sums) {
  const int idx = blockIdx.x * 256 + threadIdx.x;
  if (idx < 200) sums[idx] = 0.f;
  if (idx >= 16 * 4 * NCP * 8) return;
  const int e = idx & 7;
  int rest = idx >> 3;
  const int n = rest % NCP;
  rest /= NCP;
  const int g = rest & 3;
  const int t = rest >> 2;
  const int k = t * 32 + 4 * g + ((e < 4) ? e : (12 + e));
  float v = (n < NC) ? W[n * DIM + k] : 0.f;
  wp[idx] = (bf16)v;
}

// ---- k2: tmp = relu(X@Wt+b); write U (bf16, padded 128), Vt/Zt (bf16 transposed),
//          T (f32 -> out cols 100..199), column sums. No LDS, no barriers.
__global__ __launch_bounds__(512) void k2_main(
    const float* __restrict__ X, const bf16* __restrict__ Wp,
    const float* __restrict__ bias, float* __restrict__ out,
    bf16* __restrict__ U, bf16* __restrict__ Vt, bf16* __restrict__ Zt,
    float* __restrict__ sumU, float* __restrict__ sumV) {
  const int tid  = threadIdx.x;
  const int lane = tid & 63;
  const int wave = tid >> 6;
  const int wm = wave >> 2;   // 0..1 (32-row group)
  const int wn = wave & 3;    // 0..3 (112-col quarter)
  const int m  = lane & 15;
  const int g  = lane >> 4;
  const int rb = blockIdx.x * 64 + wm * 32;

  f32x4 acc[2][7];
#pragma unroll
  for (int i = 0; i < 2; ++i)
#pragma unroll
    for (int j = 0; j < 7; ++j) acc[i][j] = (f32x4){0.f, 0.f, 0.f, 0.f};

  int r0 = rb + m;      if (r0 > NROWS - 1) r0 = NROWS - 1;
  int r1 = rb + 16 + m; if (r1 > NROWS - 1) r1 = NROWS - 1;
  const float* xp0 = X + (size_t)r0 * DIM + 4 * g;
  const float* xp1 = X + (size_t)r1 * DIM + 4 * g;
  const char* wb = (const char*)Wp + (size_t)(g * NCP + wn * 112 + m) * 16;

  // 2-deep X prefetch (t=0, t=1)
  f32x4 xa[2][4];
  xa[0][0] = *(const f32x4*)(xp0);
  xa[0][1] = *(const f32x4*)(xp0 + 16);
  xa[0][2] = *(const f32x4*)(xp1);
  xa[0][3] = *(const f32x4*)(xp1 + 16);
  xa[1][0] = *(const f32x4*)(xp0 + 32);
  xa[1][1] = *(const f32x4*)(xp0 + 48);
  xa[1][2] = *(const f32x4*)(xp1 + 32);
  xa[1][3] = *(const f32x4*)(xp1 + 48);

  // 1-deep B prefetch (t=0)
  bf16x8 bb[2][7];
#pragma unroll
  for (int nf = 0; nf < 7; ++nf)
    bb[0][nf] = *(const bf16x8*)(wb + nf * 256);

#pragma unroll
  for (int t = 0; t < 16; ++t) {
    const int cb = t & 1;
    bf16x8 af0 = {(bf16)xa[cb][0].x, (bf16)xa[cb][0].y, (bf16)xa[cb][0].z, (bf16)xa[cb][0].w,
                  (bf16)xa[cb][1].x, (bf16)xa[cb][1].y, (bf16)xa[cb][1].z, (bf16)xa[cb][1].w};
    bf16x8 af1 = {(bf16)xa[cb][2].x, (bf16)xa[cb][2].y, (bf16)xa[cb][2].z, (bf16)xa[cb][2].w,
                  (bf16)xa[cb][3].x, (bf16)xa[cb][3].y, (bf16)xa[cb][3].z, (bf16)xa[cb][3].w};
    if (t + 2 < 16) {
      xa[cb][0] = *(const f32x4*)(xp0 + (t + 2) * 32);
      xa[cb][1] = *(const f32x4*)(xp0 + (t + 2) * 32 + 16);
      xa[cb][2] = *(const f32x4*)(xp1 + (t + 2) * 32);
      xa[cb][3] = *(const f32x4*)(xp1 + (t + 2) * 32 + 16);
    }
    if (t + 1 < 16) {
#pragma unroll
      for (int nf = 0; nf < 7; ++nf)
        bb[cb ^ 1][nf] = *(const bf16x8*)(wb + (size_t)(t + 1) * 28672 + nf * 256);
    }
#pragma unroll
    for (int nf = 0; nf < 7; ++nf) {
      acc[0][nf] = __builtin_amdgcn_mfma_f32_16x16x32_bf16(af0, bb[cb][nf], acc[0][nf], 0, 0, 0);
      acc[1][nf] = __builtin_amdgcn_mfma_f32_16x16x32_bf16(af1, bb[cb][nf], acc[1][nf], 0, 0, 0);
    }
  }

  // epilogue: bias+relu, scatter U / Vt / Zt / T, column sums
  float csum[7];
#pragma unroll
  for (int nf = 0; nf < 7; ++nf) csum[nf] = 0.f;

#pragma unroll
  for (int mf = 0; mf < 2; ++mf) {
#pragma unroll
    for (int nf = 0; nf < 7; ++nf) {
      const int c = wn * 112 + nf * 16 + m;
      const float bv = (c < NC) ? bias[c] : 0.f;
#pragma unroll
      for (int r = 0; r < 4; ++r) {
        const int row = rb + mf * 16 + 4 * g + r;
        float v = fmaxf(acc[mf][nf][r] + bv, 0.f);
        if (row < NROWS) {
          if (c < 128) U[(size_t)row * 128 + c] = (c < 100) ? (bf16)v : (bf16)0.f;
          if (c >= 100 && c < 200) Vt[(size_t)(c - 100) * NROWS + row] = (bf16)v;
          if (c >= 200 && c < 300) Zt[(size_t)(c - 200) * NROWS + row] = (bf16)v;
          if (c >= 300 && c < NC)  out[(size_t)row * 200 + 100 + (c - 300)] = v;
          if (c < 200) csum[nf] += v;
        }
      }
    }
  }
#pragma unroll
  for (int nf = 0; nf < 7; ++nf) {
    float s = csum[nf];
    s += __shfl_xor(s, 16, 64);
    s += __shfl_xor(s, 32, 64);
    if (lane < 16) {
      const int c = wn * 112 + nf * 16 + lane;
      if (c < 100) atomicAdd(&sumU[c], s);
      else if (c < 200) atomicAdd(&sumV[c - 100], s);
    }
  }
}

// ---- k3: partial VtZ per 512-row block via MFMA, straight from Vt/Zt (no LDS) ----
// Fragment rows/cols >= 100 read adjacent ws data (finite bf16) and are discarded.
__global__ __launch_bounds__(512) void k3_vtz(
    const bf16* __restrict__ Vt, const bf16* __restrict__ Zt,
    bf16* __restrict__ part) {
  const int lane = threadIdx.x & 63;
  const int wave = threadIdx.x >> 6;
  if (wave >= 7) return;
  const int m = lane & 15, g = lane >> 4;
  const int rbase = blockIdx.x * 512;
  int nks = (NROWS - rbase) >> 5;
  if (nks > 16) nks = 16;

  f32x4 acc[7];
#pragma unroll
  for (int j = 0; j < 7; ++j) acc[j] = (f32x4){0.f, 0.f, 0.f, 0.f};

  const int i2 = wave * 16 + m;
  const bf16* va = Vt + (size_t)i2 * NROWS;
  for (int ks = 0; ks < nks; ++ks) {
    const int k0 = rbase + ks * 32 + 4 * g;
    bf16x4 A0 = *(const bf16x4*)(va + k0);
    bf16x4 A1 = *(const bf16x4*)(va + k0 + 16);
    bf16x8 af = {A0[0], A0[1], A0[2], A0[3], A1[0], A1[1], A1[2], A1[3]};
#pragma unroll
    for (int nf = 0; nf < 7; ++nf) {
      const bf16* zb = Zt + (size_t)(nf * 16 + m) * NROWS + k0;
      bf16x4 B0 = *(const bf16x4*)(zb);
      bf16x4 B1 = *(const bf16x4*)(zb + 16);
      bf16x8 bf_ = {B0[0], B0[1], B0[2], B0[3], B1[0], B1[1], B1[2], B1[3]};
      acc[nf] = __builtin_amdgcn_mfma_f32_16x16x32_bf16(af, bf_, acc[nf], 0, 0, 0);
    }
  }
  bf16* pb = part + (size_t)blockIdx.x * 12544;
#pragma unroll
  for (int nf = 0; nf < 7; ++nf)
#pragma unroll
    for (int r = 0; r < 4; ++r) {
      const int ii = wave * 16 + 4 * g + r;
      const int jj = nf * 16 + m;
      pb[ii * 112 + jj] = (bf16)acc[nf][r];
    }
}

// ---- k4a: Dscale ----
__global__ void k4a_norm(const float* __restrict__ sumU, const float* __restrict__ sumV,
                         float* __restrict__ dsc) {
  const int l = threadIdx.x;  // 64
  float v = 0.f;
  if (l < 50) v = sumU[l] * sumV[l] + sumU[l + 50] * sumV[l + 50];
#pragma unroll
  for (int off = 32; off > 0; off >>= 1) v += __shfl_down(v, off, 64);
  if (l == 0) dsc[0] = 1.f / (v * (1.f / (float)NROWS) + 1e-6f);
}

// ---- k4b1: reduce 196 bf16 partials -> 7 f32 groups (of 28) ----
__global__ void k4b1_reduce(const bf16* __restrict__ part, float* __restrict__ part2) {
  const int b = blockIdx.x;          // 343 = 7*49
  const int grp = b / 49;
  const int off = (b % 49) * 256 + threadIdx.x;
  if (off >= 12544) return;
  float s = 0.f;
#pragma unroll 4
  for (int q = 0; q < 28; ++q)
    s += (float)part[(size_t)(grp * 28 + q) * 12544 + off];
  part2[grp * 12544 + off] = s;
}

// ---- k4b2: final 7-sum, scale by Dscale, store transposed bf16 [j][128] ----
__global__ void k4b2_final(const float* __restrict__ part2, const float* __restrict__ dsc,
                           bf16* __restrict__ vtzt) {
  const int idx = blockIdx.x * 256 + threadIdx.x;   // 49 blocks
  if (idx < 1792) vtzt[(idx >> 4) * 128 + 112 + (idx & 15)] = (bf16)0.f;
  if (idx >= 12544) return;
  const int i = idx / 112;   // k index (U column) 0..111
  const int j = idx % 112;   // res output column
  float s = 0.f;
#pragma unroll
  for (int grp = 0; grp < 7; ++grp) s += part2[grp * 12544 + idx];
  vtzt[j * 128 + i] = (bf16)(s * dsc[0]);
}

// ---- k5: res = U @ VtZS -> out[:, 0:100] ----
__global__ __launch_bounds__(256) void k5_res(
    const bf16* __restrict__ U, const bf16* __restrict__ vtzt,
    float* __restrict__ out) {
  const int tid = threadIdx.x;
  const int lane = tid & 63;
  const int wave = tid >> 6;
  const int m = lane & 15, g = lane >> 4;
  const int rb = blockIdx.x * 128 + wave * 32;

  f32x4 acc[2][7];
#pragma unroll
  for (int i = 0; i < 2; ++i)
#pragma unroll
    for (int j = 0; j < 7; ++j) acc[i][j] = (f32x4){0.f, 0.f, 0.f, 0.f};

  int r0 = rb + m;      if (r0 > NROWS - 1) r0 = NROWS - 1;
  int r1 = rb + 16 + m; if (r1 > NROWS - 1) r1 = NROWS - 1;
  const bf16* u0 = U + (size_t)r0 * 128 + 4 * g;
  const bf16* u1 = U + (size_t)r1 * 128 + 4 * g;
  const bf16* vb = vtzt + 4 * g;

#pragma unroll
  for (int ks = 0; ks < 4; ++ks) {
    bf16x4 A00 = *(const bf16x4*)(u0 + ks * 32);
    bf16x4 A01 = *(const bf16x4*)(u0 + ks * 32 + 16);
    bf16x4 A10 = *(const bf16x4*)(u1 + ks * 32);
    bf16x4 A11 = *(const bf16x4*)(u1 + ks * 32 + 16);
    bf16x8 af0 = {A00[0], A00[1], A00[2], A00[3], A01[0], A01[1], A01[2], A01[3]};
    bf16x8 af1 = {A10[0], A10[1], A10[2], A10[3], A11[0], A11[1], A11[2], A11[3]};
#pragma unroll
    for (int nf = 0; nf < 7; ++nf) {
      const int n = nf * 16 + m;
      bf16x4 B0 = *(const bf16x4*)(vb + n * 128 + ks * 32);
      bf16x4 B1 = *(const bf16x4*)(vb + n * 128 + ks * 32 + 16);
      bf16x8 bfr = {B0[0], B0[1], B0[2], B0[3], B1[0], B1[1], B1[2], B1[3]};
      acc[0][nf] = __builtin_amdgcn_mfma_f32_16x16x32_bf16(af0, bfr, acc[0][nf], 0, 0, 0);
      acc[1][nf] = __builtin_amdgcn_mfma_f32_16x16x32_bf16(af1, bfr, acc[1][nf], 0, 0, 0);
    }
  }
#pragma unroll
  for (int mf = 0; mf < 2; ++mf)
#pragma unroll
    for (int nf = 0; nf < 7; ++nf)
#pragma unroll
      for (int r = 0; r < 4; ++r) {
        const int row = rb + mf * 16 + 4 * g + r;
        const int c = nf * 16 + m;
        if (row < NROWS && c < 100)
          out[(size_t)row * 200 + c] = acc[mf][nf][r];
      }
}

extern "C" void kernel_launch(void* const* d_in, const int* in_sizes, int n_in,
                              void* d_out, int out_size, void* d_ws, size_t ws_size,
                              hipStream_t stream) {
  const float* X = (const float*)d_in[0];
  const float* W = (const float*)d_in[1];
  const float* b = (const float*)d_in[2];
  float* out = (float*)d_out;
  char* ws = (char*)d_ws;
  if (ws_size < WS_NEED) return;

  bf16* wp     = (bf16*)(ws + WS_WP);
  float* sumU  = (float*)(ws + WS_SUMU);
  float* sumV  = (float*)(ws + WS_SUMV);
  float* dsc   = (float*)(ws + WS_DSC);
  bf16* vtzt   = (bf16*)(ws + WS_VTZT);
  bf16* U      = (bf16*)(ws + WS_U);
  bf16* Vtb    = (bf16*)(ws + WS_VT);
  bf16* Ztb    = (bf16*)(ws + WS_ZT);
  bf16* part   = (bf16*)(ws + WS_PART);
  float* part2 = (float*)(ws + WS_PART2);

  k1_prep<<<896, 256, 0, stream>>>(W, wp, sumU);
  k2_main<<<1563, 512, 0, stream>>>(X, wp, b, out, U, Vtb, Ztb, sumU, sumV);
  k3_vtz<<<196, 512, 0, stream>>>(Vtb, Ztb, part);
  k4a_norm<<<1, 64, 0, stream>>>(sumU, sumV, dsc);
  k4b1_reduce<<<343, 256, 0, stream>>>(part, part2);
  k4b2_final<<<49, 256, 0, stream>>>(part2, dsc, vtzt);
  k5_res<<<782, 256, 0, stream>>>(U, vtzt, out);
}

// Round 3
// 274.130 us; speedup vs baseline: 1.7193x; 1.3603x over previous
//
#include <hip/hip_runtime.h>
#include <cstdint>

typedef __bf16 bf16;
typedef __attribute__((ext_vector_type(8))) __bf16 bf16x8;
typedef __attribute__((ext_vector_type(4))) __bf16 bf16x4;
typedef __attribute__((ext_vector_type(4))) float f32x4;

#define NROWS 100000
#define DIM   512
#define NC    400

// ---- workspace layout (bytes) ---- (proven bound: ws >= 71041536)
#define WS_WP    0u          // packed W bf16: 16*2*4*224*8 = 229376 elems = 458752 B
#define WS_SUMU  458752u
#define WS_SUMV  459152u
#define WS_DSC   459552u
#define WS_VTZT  459776u     // [112][128] bf16
#define WS_U     524288u     // [100000][128] bf16
#define WS_VT    26124288u   // V^T [100][100000] bf16
#define WS_ZT    46124288u   // Z^T [100][100000] bf16
#define WS_PART  66124288u   // 196 x 12544 bf16
#define WS_NEED  71041536u
#define WS_PART2 WS_WP       // reuse dead wp region after k2

__device__ __forceinline__ void gload_lds16(const void* g, void* l) {
  __builtin_amdgcn_global_load_lds(
      (const __attribute__((address_space(1))) uint32_t*)g,
      (__attribute__((address_space(3))) uint32_t*)l,
      16, 0, 0);
}

// ---- k1: pack W -> [t][h][g][224][8] bf16 (14336 B contiguous per (t,h)); zero sums
// k = t*32 + 4g + (e<4 ? e : 12+e) ; col = h*224 + n
__global__ void k1_prep(const float* __restrict__ W, bf16* __restrict__ wp,
                        float* __restrict__ sums) {
  const int idx = blockIdx.x * 256 + threadIdx.x;
  if (idx < 200) sums[idx] = 0.f;
  if (idx >= 16 * 2 * 4 * 224 * 8) return;
  const int e = idx & 7;
  int r = idx >> 3;
  const int n = r % 224; r /= 224;
  const int g = r & 3;   r >>= 2;
  const int h = r & 1;
  const int t = r >> 1;
  const int k = t * 32 + 4 * g + ((e < 4) ? e : (12 + e));
  const int col = h * 224 + n;
  wp[idx] = (bf16)((col < NC) ? W[col * DIM + k] : 0.f);
}

// ---- k2: relu(X@Wt+b); U (bf16 pad128), Vt/Zt (bf16 transposed), T (f32->out),
//          col sums. 2-phase double-buffered LDS, gload_lds for W, reg-staged X.
__global__ __launch_bounds__(256, 2) void k2_main(
    const float* __restrict__ X, const bf16* __restrict__ Wp,
    const float* __restrict__ bias, float* __restrict__ out,
    bf16* __restrict__ U, bf16* __restrict__ Vt, bf16* __restrict__ Zt,
    float* __restrict__ sumU, float* __restrict__ sumV) {
  __shared__ __align__(16) bf16 Ab[2][64 * 40];   // [row][32k + 8 pad], 5120 B each
  __shared__ __align__(16) bf16 Bb[2][7168];      // [g][224][8], 14336 B each

  const int tid  = threadIdx.x;
  const int lane = tid & 63;
  const int wave = tid >> 6;        // 0..3
  const int wm = wave & 1;          // 32-row half
  const int wn = wave >> 1;         // 112-col half
  const int m  = lane & 15;
  const int g  = lane >> 4;
  const int bi = blockIdx.x;
  const int h  = bi & 1;            // 224-col half of N
  const int rb = (bi >> 1) * 64;

  f32x4 acc[2][7];
#pragma unroll
  for (int i = 0; i < 2; ++i)
#pragma unroll
    for (int j = 0; j < 7; ++j) acc[i][j] = (f32x4){0.f, 0.f, 0.f, 0.f};

  // A staging: thread -> row=tid>>2 (0..63), 8 consecutive k (aq*8)
  const int arow = tid >> 2;
  const int aq   = tid & 3;
  int gr = rb + arow; if (gr > NROWS - 1) gr = NROWS - 1;
  const float* xsrc = X + (size_t)gr * DIM + aq * 8;
  const int awoff = arow * 40 + aq * 8;     // elems; byte addr = arow*80+aq*16 (16B aligned)

  // prologue: stage t=0 into buf0
  {
    f32x4 p0 = *(const f32x4*)(xsrc);
    f32x4 p1 = *(const f32x4*)(xsrc + 4);
    const char* wsrc = (const char*)Wp + (size_t)(0 * 2 + h) * 14336;
    for (int c = wave; c < 14; c += 4)
      gload_lds16(wsrc + c * 1024 + lane * 16, (char*)&Bb[0][0] + c * 1024);
    bf16x8 w8 = {(bf16)p0.x, (bf16)p0.y, (bf16)p0.z, (bf16)p0.w,
                 (bf16)p1.x, (bf16)p1.y, (bf16)p1.z, (bf16)p1.w};
    *(bf16x8*)&Ab[0][awoff] = w8;
    __syncthreads();
  }

  for (int t = 0; t < 16; ++t) {
    const int cur = t & 1;
    const int nxt = cur ^ 1;
    f32x4 p0, p1;
    if (t < 15) {
      // issue next-tile loads first (T14: issue-early)
      p0 = *(const f32x4*)(xsrc + (t + 1) * 32);
      p1 = *(const f32x4*)(xsrc + (t + 1) * 32 + 4);
      const char* wsrc = (const char*)Wp + (size_t)((t + 1) * 2 + h) * 14336;
      for (int c = wave; c < 14; c += 4)
        gload_lds16(wsrc + c * 1024 + lane * 16, (char*)&Bb[nxt][0] + c * 1024);
    }
    // compute current tile
    const bf16* Ac = &Ab[cur][0];
    const bf16* Bc = &Bb[cur][0];
    const int ar0 = (wm * 32 + m) * 40 + g * 4;        // elems
    bf16x4 lo0 = *(const bf16x4*)(Ac + ar0);
    bf16x4 hi0 = *(const bf16x4*)(Ac + ar0 + 16);
    bf16x4 lo1 = *(const bf16x4*)(Ac + ar0 + 16 * 40);
    bf16x4 hi1 = *(const bf16x4*)(Ac + ar0 + 16 * 40 + 16);
    bf16x8 af0 = {lo0[0], lo0[1], lo0[2], lo0[3], hi0[0], hi0[1], hi0[2], hi0[3]};
    bf16x8 af1 = {lo1[0], lo1[1], lo1[2], lo1[3], hi1[0], hi1[1], hi1[2], hi1[3]};
#pragma unroll
    for (int nf = 0; nf < 7; ++nf) {
      const int n = wn * 112 + nf * 16 + m;
      bf16x8 bfr = *(const bf16x8*)(Bc + (g * 224 + n) * 8);
      acc[0][nf] = __builtin_amdgcn_mfma_f32_16x16x32_bf16(af0, bfr, acc[0][nf], 0, 0, 0);
      acc[1][nf] = __builtin_amdgcn_mfma_f32_16x16x32_bf16(af1, bfr, acc[1][nf], 0, 0, 0);
    }
    if (t < 15) {
      // write-late: cvt waits on p0/p1 after the MFMA cluster
      bf16x8 w8 = {(bf16)p0.x, (bf16)p0.y, (bf16)p0.z, (bf16)p0.w,
                   (bf16)p1.x, (bf16)p1.y, (bf16)p1.z, (bf16)p1.w};
      *(bf16x8*)&Ab[nxt][awoff] = w8;
    }
    __syncthreads();
  }

  // epilogue: bias+relu, scatter U / Vt / Zt / T, column sums
  float csum[7];
#pragma unroll
  for (int nf = 0; nf < 7; ++nf) csum[nf] = 0.f;

#pragma unroll
  for (int mf = 0; mf < 2; ++mf) {
#pragma unroll
    for (int nf = 0; nf < 7; ++nf) {
      const int c = h * 224 + wn * 112 + nf * 16 + m;
      const float bv = (c < NC) ? bias[c] : 0.f;
#pragma unroll
      for (int r = 0; r < 4; ++r) {
        const int row = rb + wm * 32 + mf * 16 + 4 * g + r;
        float v = fmaxf(acc[mf][nf][r] + bv, 0.f);
        if (row < NROWS) {
          if (c < 128) U[(size_t)row * 128 + c] = (c < 100) ? (bf16)v : (bf16)0.f;
          if (c >= 100 && c < 200) Vt[(size_t)(c - 100) * NROWS + row] = (bf16)v;
          if (c >= 200 && c < 300) Zt[(size_t)(c - 200) * NROWS + row] = (bf16)v;
          if (c >= 300 && c < NC)  out[(size_t)row * 200 + 100 + (c - 300)] = v;
          if (c < 200) csum[nf] += v;
        }
      }
    }
  }
#pragma unroll
  for (int nf = 0; nf < 7; ++nf) {
    float s = csum[nf];
    s += __shfl_xor(s, 16, 64);
    s += __shfl_xor(s, 32, 64);
    if (lane < 16) {
      const int c = h * 224 + wn * 112 + nf * 16 + lane;
      if (c < 100) atomicAdd(&sumU[c], s);
      else if (c < 200) atomicAdd(&sumV[c - 100], s);
    }
  }
}

// ---- k3: partial VtZ per 512-row block via MFMA from Vt/Zt (no LDS) ----
__global__ __launch_bounds__(512) void k3_vtz(
    const bf16* __restrict__ Vt, const bf16* __restrict__ Zt,
    bf16* __restrict__ part) {
  const int lane = threadIdx.x & 63;
  const int wave = threadIdx.x >> 6;
  if (wave >= 7) return;
  const int m = lane & 15, g = lane >> 4;
  const int rbase = blockIdx.x * 512;
  int nks = (NROWS - rbase) >> 5;
  if (nks > 16) nks = 16;

  f32x4 acc[7];
#pragma unroll
  for (int j = 0; j < 7; ++j) acc[j] = (f32x4){0.f, 0.f, 0.f, 0.f};

  const int i2 = wave * 16 + m;
  const bf16* va = Vt + (size_t)i2 * NROWS;
  for (int ks = 0; ks < nks; ++ks) {
    const int k0 = rbase + ks * 32 + 4 * g;
    bf16x4 A0 = *(const bf16x4*)(va + k0);
    bf16x4 A1 = *(const bf16x4*)(va + k0 + 16);
    bf16x8 af = {A0[0], A0[1], A0[2], A0[3], A1[0], A1[1], A1[2], A1[3]};
#pragma unroll
    for (int nf = 0; nf < 7; ++nf) {
      const bf16* zb = Zt + (size_t)(nf * 16 + m) * NROWS + k0;
      bf16x4 B0 = *(const bf16x4*)(zb);
      bf16x4 B1 = *(const bf16x4*)(zb + 16);
      bf16x8 bf_ = {B0[0], B0[1], B0[2], B0[3], B1[0], B1[1], B1[2], B1[3]};
      acc[nf] = __builtin_amdgcn_mfma_f32_16x16x32_bf16(af, bf_, acc[nf], 0, 0, 0);
    }
  }
  bf16* pb = part + (size_t)blockIdx.x * 12544;
#pragma unroll
  for (int nf = 0; nf < 7; ++nf)
#pragma unroll
    for (int r = 0; r < 4; ++r) {
      const int ii = wave * 16 + 4 * g + r;
      const int jj = nf * 16 + m;
      pb[ii * 112 + jj] = (bf16)acc[nf][r];
    }
}

// ---- k4a: Dscale ----
__global__ void k4a_norm(const float* __restrict__ sumU, const float* __restrict__ sumV,
                         float* __restrict__ dsc) {
  const int l = threadIdx.x;  // 64
  float v = 0.f;
  if (l < 50) v = sumU[l] * sumV[l] + sumU[l + 50] * sumV[l + 50];
#pragma unroll
  for (int off = 32; off > 0; off >>= 1) v += __shfl_down(v, off, 64);
  if (l == 0) dsc[0] = 1.f / (v * (1.f / (float)NROWS) + 1e-6f);
}

// ---- k4b1: reduce 196 bf16 partials -> 7 f32 groups (of 28) ----
__global__ void k4b1_reduce(const bf16* __restrict__ part, float* __restrict__ part2) {
  const int b = blockIdx.x;          // 343 = 7*49
  const int grp = b / 49;
  const int off = (b % 49) * 256 + threadIdx.x;
  if (off >= 12544) return;
  float s = 0.f;
#pragma unroll 4
  for (int q = 0; q < 28; ++q)
    s += (float)part[(size_t)(grp * 28 + q) * 12544 + off];
  part2[grp * 12544 + off] = s;
}

// ---- k4b2: final 7-sum, scale by Dscale, store transposed bf16 [j][128] ----
__global__ void k4b2_final(const float* __restrict__ part2, const float* __restrict__ dsc,
                           bf16* __restrict__ vtzt) {
  const int idx = blockIdx.x * 256 + threadIdx.x;   // 49 blocks
  if (idx < 1792) vtzt[(idx >> 4) * 128 + 112 + (idx & 15)] = (bf16)0.f;
  if (idx >= 12544) return;
  const int i = idx / 112;
  const int j = idx % 112;
  float s = 0.f;
#pragma unroll
  for (int grp = 0; grp < 7; ++grp) s += part2[grp * 12544 + idx];
  vtzt[j * 128 + i] = (bf16)(s * dsc[0]);
}

// ---- k5: res = U @ VtZS -> out[:, 0:100] ----
__global__ __launch_bounds__(256) void k5_res(
    const bf16* __restrict__ U, const bf16* __restrict__ vtzt,
    float* __restrict__ out) {
  const int tid = threadIdx.x;
  const int lane = tid & 63;
  const int wave = tid >> 6;
  const int m = lane & 15, g = lane >> 4;
  const int rb = blockIdx.x * 128 + wave * 32;

  f32x4 acc[2][7];
#pragma unroll
  for (int i = 0; i < 2; ++i)
#pragma unroll
    for (int j = 0; j < 7; ++j) acc[i][j] = (f32x4){0.f, 0.f, 0.f, 0.f};

  int r0 = rb + m;      if (r0 > NROWS - 1) r0 = NROWS - 1;
  int r1 = rb + 16 + m; if (r1 > NROWS - 1) r1 = NROWS - 1;
  const bf16* u0 = U + (size_t)r0 * 128 + 4 * g;
  const bf16* u1 = U + (size_t)r1 * 128 + 4 * g;
  const bf16* vb = vtzt + 4 * g;

#pragma unroll
  for (int ks = 0; ks < 4; ++ks) {
    bf16x4 A00 = *(const bf16x4*)(u0 + ks * 32);
    bf16x4 A01 = *(const bf16x4*)(u0 + ks * 32 + 16);
    bf16x4 A10 = *(const bf16x4*)(u1 + ks * 32);
    bf16x4 A11 = *(const bf16x4*)(u1 + ks * 32 + 16);
    bf16x8 af0 = {A00[0], A00[1], A00[2], A00[3], A01[0], A01[1], A01[2], A01[3]};
    bf16x8 af1 = {A10[0], A10[1], A10[2], A10[3], A11[0], A11[1], A11[2], A11[3]};
#pragma unroll
    for (int nf = 0; nf < 7; ++nf) {
      const int n = nf * 16 + m;
      bf16x4 B0 = *(const bf16x4*)(vb + n * 128 + ks * 32);
      bf16x4 B1 = *(const bf16x4*)(vb + n * 128 + ks * 32 + 16);
      bf16x8 bfr = {B0[0], B0[1], B0[2], B0[3], B1[0], B1[1], B1[2], B1[3]};
      acc[0][nf] = __builtin_amdgcn_mfma_f32_16x16x32_bf16(af0, bfr, acc[0][nf], 0, 0, 0);
      acc[1][nf] = __builtin_amdgcn_mfma_f32_16x16x32_bf16(af1, bfr, acc[1][nf], 0, 0, 0);
    }
  }
#pragma unroll
  for (int mf = 0; mf < 2; ++mf)
#pragma unroll
    for (int nf = 0; nf < 7; ++nf)
#pragma unroll
      for (int r = 0; r < 4; ++r) {
        const int row = rb + mf * 16 + 4 * g + r;
        const int c = nf * 16 + m;
        if (row < NROWS && c < 100)
          out[(size_t)row * 200 + c] = acc[mf][nf][r];
      }
}

extern "C" void kernel_launch(void* const* d_in, const int* in_sizes, int n_in,
                              void* d_out, int out_size, void* d_ws, size_t ws_size,
                              hipStream_t stream) {
  const float* X = (const float*)d_in[0];
  const float* W = (const float*)d_in[1];
  const float* b = (const float*)d_in[2];
  float* out = (float*)d_out;
  char* ws = (char*)d_ws;
  if (ws_size < WS_NEED) return;

  bf16* wp     = (bf16*)(ws + WS_WP);
  float* sumU  = (float*)(ws + WS_SUMU);
  float* sumV  = (float*)(ws + WS_SUMV);
  float* dsc   = (float*)(ws + WS_DSC);
  bf16* vtzt   = (bf16*)(ws + WS_VTZT);
  bf16* U      = (bf16*)(ws + WS_U);
  bf16* Vtb    = (bf16*)(ws + WS_VT);
  bf16* Ztb    = (bf16*)(ws + WS_ZT);
  bf16* part   = (bf16*)(ws + WS_PART);
  float* part2 = (float*)(ws + WS_PART2);

  k1_prep<<<896, 256, 0, stream>>>(W, wp, sumU);
  k2_main<<<3126, 256, 0, stream>>>(X, wp, b, out, U, Vtb, Ztb, sumU, sumV);
  k3_vtz<<<196, 512, 0, stream>>>(Vtb, Ztb, part);
  k4a_norm<<<1, 64, 0, stream>>>(sumU, sumV, dsc);
  k4b1_reduce<<<343, 256, 0, stream>>>(part, part2);
  k4b2_final<<<49, 256, 0, stream>>>(part2, dsc, vtzt);
  k5_res<<<782, 256, 0, stream>>>(U, vtzt, out);
}